// Round 9
// baseline (445.416 us; speedup 1.0000x reference)
//
#include <hip/hip_runtime.h>

#define CIN   64
#define COUT  64
#define TT    12
#define FEAT  (CIN * TT)   // 768
#define UROW  (FEAT / 2)   // 384 uints (2 bf16) per row in xh2
#define UPASS 192          // uints per pass slice (6 tt x 64 c / 2)

typedef unsigned int uint32;
typedef unsigned long long u64;
typedef float  __attribute__((ext_vector_type(4))) f32x4;
typedef float  __attribute__((ext_vector_type(2))) f32x2;

#define DEG_SCALE 1048576.0f   // 2^20 fixed point for edge-weight sums

__device__ __forceinline__ uint32 bf16rne(float f) {
    uint32 u = __float_as_uint(f);
    return (u + 0x7fffu + ((u >> 16) & 1)) >> 16;
}
__device__ __forceinline__ uint32 pk(float lo, float hi) {
    return bf16rne(lo) | (bf16rne(hi) << 16);
}

// ---------- transpose-convert: xh2[n][tt][c] (tt-major), unit = (n, channel-pair m) ----------
// thread unit idx: n = idx>>5, m = idx&31 -> reads x[n][2m..2m+1][0..11] = 24 contiguous floats
__device__ __forceinline__ void cvtT_range(const float* __restrict__ x,
                                           uint32* __restrict__ xh2,
                                           int lo, int hi, int tid, int stride) {
    for (int idx = lo + tid; idx < hi; idx += stride) {
        int n = idx >> 5, m = idx & 31;
        const f32x4* s = (const f32x4*)(x + (size_t)n * FEAT + m * 24);
        f32x4 q0 = __builtin_nontemporal_load(&s[0]);
        f32x4 q1 = __builtin_nontemporal_load(&s[1]);
        f32x4 q2 = __builtin_nontemporal_load(&s[2]);
        f32x4 q3 = __builtin_nontemporal_load(&s[3]);
        f32x4 q4 = __builtin_nontemporal_load(&s[4]);
        f32x4 q5 = __builtin_nontemporal_load(&s[5]);
        uint32* d = xh2 + (size_t)n * UROW + m;
        // q0..q2 = channel 2m (tt 0..11), q3..q5 = channel 2m+1 (tt 0..11)
        d[0 * 32] = pk(q0.x, q3.x);  d[1 * 32] = pk(q0.y, q3.y);
        d[2 * 32] = pk(q0.z, q3.z);  d[3 * 32] = pk(q0.w, q3.w);
        d[4 * 32] = pk(q1.x, q4.x);  d[5 * 32] = pk(q1.y, q4.y);
        d[6 * 32] = pk(q1.z, q4.z);  d[7 * 32] = pk(q1.w, q4.w);
        d[8 * 32] = pk(q2.x, q5.x);  d[9 * 32] = pk(q2.y, q5.y);
        d[10 * 32] = pk(q2.z, q5.z); d[11 * 32] = pk(q2.w, q5.w);
    }
}

// ---------- L1: degree atomics + cvt half A ----------
__global__ __launch_bounds__(256) void k_deg_cvt(
    const float* __restrict__ x, uint32* __restrict__ xh2, int ulo, int uhi, int nbCvt,
    const int* __restrict__ dst, const float* __restrict__ ea,
    u64* __restrict__ deg64, int e_cnt)
{
    int bid = blockIdx.x;
    if (bid < nbCvt) {
        cvtT_range(x, xh2, ulo, uhi, bid * 256 + threadIdx.x, nbCvt * 256);
    } else {
        int e = (bid - nbCvt) * 256 + threadIdx.x;
        if (e < e_cnt) {
            u64 v = ((u64)1 << 32) | (u64)(uint32)(ea[e] * DEG_SCALE + 0.5f);
            atomicAdd(&deg64[dst[e]], v);
        }
    }
}

// ---------- L2: dis = rsqrt(1 + sum_ea); block-reduce cnt into partial[] ----------
__global__ __launch_bounds__(256) void k_disred(const u64* __restrict__ deg64,
                                                float* __restrict__ dis,
                                                int* __restrict__ partial, int n) {
    __shared__ int red[256];
    int t = threadIdx.x;
    int i = blockIdx.x * 256 + t;
    int cnt = 0;
    if (i < n) {
        u64 v = deg64[i];
        cnt = (int)(v >> 32);
        dis[i] = rsqrtf(1.0f + (float)(uint32)v * (1.0f / DEG_SCALE));
    }
    red[t] = cnt;
    __syncthreads();
    for (int off = 128; off > 0; off >>= 1) {
        if (t < off) red[t] += red[t + off];
        __syncthreads();
    }
    if (t == 0) partial[blockIdx.x] = red[0];
}

// ---------- L3: per-element scan; each block redundantly reduces partial[] ----------
__global__ __launch_bounds__(256) void k_scanwrite(const u64* __restrict__ deg64,
                                                   const int* __restrict__ partial,
                                                   int nb,
                                                   int* __restrict__ rowptr,
                                                   int* __restrict__ cursor, int n) {
    __shared__ int tmp[256];
    __shared__ int pred[256];
    int t = threadIdx.x;
    int bid = blockIdx.x;
    int i = bid * 256 + t;

    int pv = (t < nb) ? partial[t] : 0;
    pred[t] = (t < bid) ? pv : 0;
    int v = (i < n) ? (int)(deg64[i] >> 32) : 0;
    tmp[t] = v;
    __syncthreads();
    for (int off = 128; off > 0; off >>= 1) {
        if (t < off) pred[t] += pred[t + off];
        __syncthreads();
    }
    for (int off = 1; off < 256; off <<= 1) {
        int u = (t >= off) ? tmp[t - off] : 0;
        __syncthreads();
        tmp[t] += u;
        __syncthreads();
    }
    int blockOff = pred[0];
    int excl = tmp[t] - v + blockOff;
    if (i < n) { rowptr[i] = excl; cursor[i] = excl; }
    if (bid == nb - 1 && t == 255) rowptr[n] = blockOff + tmp[255];
}

// ---------- L4: scatter edges into CSR slots + cvt half B ----------
__global__ __launch_bounds__(256) void k_fill_cvt(
    const float* __restrict__ x, uint32* __restrict__ xh2, int ulo, int uhi, int nbCvt,
    const int* __restrict__ src, const int* __restrict__ dst,
    const float* __restrict__ ea, const float* __restrict__ dis,
    int* __restrict__ cursor, int2* __restrict__ csr, int e_cnt)
{
    int bid = blockIdx.x;
    if (bid < nbCvt) {
        cvtT_range(x, xh2, ulo, uhi, bid * 256 + threadIdx.x, nbCvt * 256);
    } else {
        int e = (bid - nbCvt) * 256 + threadIdx.x;
        if (e < e_cnt) {
            int s = src[e], d = dst[e];
            int pos = atomicAdd(&cursor[d], 1);
            float w = dis[s] * ea[e] * dis[d];
            int2 p; p.x = s; p.y = __float_as_int(w);
            csr[pos] = p;
        }
    }
}

// ---------- 2-pass fused aggregate + GEMM + bias + ReLU ----------
// pass p covers tt in [6p, 6p+6): contiguous 192 uints of each xh2 row.
// one block per node, 192 threads; thread t owns uint t of the pass slice
// = bf16 local idx {2t, 2t+1} = (tt_l = t>>5, c = 2t&63, c+1)
__global__ __launch_bounds__(192) void k_conv2(
    const uint32* __restrict__ xh2, const float* __restrict__ W,
    const float* __restrict__ b, const float* __restrict__ dis,
    const int* __restrict__ rowptr, const int2* __restrict__ csr,
    float* __restrict__ out, int pass)
{
    __shared__ float sAgg[2 * UPASS];   // 1.5 KB, layout: local bf16 idx = tt_l*64 + c
    __shared__ int2  sE[192];           // 1.5 KB
    __shared__ float sB[COUT];

    const int n = blockIdx.x;
    const int t = threadIdx.x;
    if (t < COUT) sB[t] = b[t];

    const int start = rowptr[n];
    const int end   = rowptr[n + 1];
    const float dn  = dis[n];
    const float selfw = dn * dn;

    const uint32* xb = xh2 + pass * UPASS;
    uint32 v = xb[(size_t)n * UROW + t];
    float a0 = selfw * __uint_as_float(v << 16);
    float a1 = selfw * __uint_as_float(v & 0xffff0000u);

    for (int base = start; base < end; base += 192) {
        int cnt = end - base; if (cnt > 192) cnt = 192;
        __syncthreads();
        if (t < cnt) sE[t] = csr[base + t];
        __syncthreads();
        for (int j = 0; j < cnt; ++j) {
            int s    = sE[j].x;
            float w  = __int_as_float(sE[j].y);
            uint32 u = xb[(size_t)s * UROW + t];
            a0 = fmaf(w, __uint_as_float(u << 16),         a0);
            a1 = fmaf(w, __uint_as_float(u & 0xffff0000u), a1);
        }
    }

    f32x2 av; av.x = a0; av.y = a1;
    *((f32x2*)&sAgg[2 * t]) = av;
    __syncthreads();

    // GEMM: out[co, tt] = relu(b[co] + sum_c W[c,co] * agg[c, tt]), tt_l = tg*2+{0,1}
    const int co = t & 63;
    const int tg = t >> 6;               // 0..2, wave-uniform
    float o0 = sB[co], o1 = sB[co];
#pragma unroll
    for (int c = 0; c < CIN; ++c) {
        float wv = W[c * COUT + co];     // hot 16 KB in L1/L2
        o0 = fmaf(wv, sAgg[(tg * 2    ) * 64 + c], o0);   // broadcast reads
        o1 = fmaf(wv, sAgg[(tg * 2 + 1) * 64 + c], o1);
    }
    f32x2 r; r.x = fmaxf(o0, 0.0f); r.y = fmaxf(o1, 0.0f);
    // out[n][co][pass*6 + tg*2 .. +1] — 8B store (addr elems even -> aligned)
    *((f32x2*)(out + (size_t)n * FEAT + co * TT + pass * 6 + tg * 2)) = r;
}

// ---------- fallback (ws too small): fp32 gather on original layout (R5) ----------
__global__ __launch_bounds__(192) void k_conv_f32(
    const float* __restrict__ xsrc, const float* __restrict__ W,
    const float* __restrict__ b, const float* __restrict__ dis,
    const int* __restrict__ rowptr, const int2* __restrict__ csr,
    float* __restrict__ out)
{
    __shared__ float sAgg[FEAT];
    __shared__ int2  sE[192];
    __shared__ float sB[COUT];

    const int n = blockIdx.x;
    const int t = threadIdx.x;
    if (t < COUT) sB[t] = b[t];

    const int start = rowptr[n];
    const int end   = rowptr[n + 1];
    const float dn  = dis[n];
    const float selfw = dn * dn;

    const f32x4* xb = (const f32x4*)xsrc;
    f32x4 v = xb[(size_t)n * (FEAT / 4) + t];
    float a0 = selfw * v.x, a1 = selfw * v.y, a2 = selfw * v.z, a3 = selfw * v.w;

    for (int base = start; base < end; base += 192) {
        int cnt = end - base; if (cnt > 192) cnt = 192;
        __syncthreads();
        if (t < cnt) sE[t] = csr[base + t];
        __syncthreads();
        for (int j = 0; j < cnt; ++j) {
            int s    = sE[j].x;
            float w  = __int_as_float(sE[j].y);
            f32x4 u = xb[(size_t)s * (FEAT / 4) + t];
            a0 = fmaf(w, u.x, a0); a1 = fmaf(w, u.y, a1);
            a2 = fmaf(w, u.z, a2); a3 = fmaf(w, u.w, a3);
        }
    }

    float4 av; av.x = a0; av.y = a1; av.z = a2; av.w = a3;
    *((float4*)&sAgg[4 * t]) = av;
    __syncthreads();

    const int co  = t & 63;
    const int tg  = t >> 6;
    const int tt0 = tg * 4;
    float o0 = sB[co], o1 = o0, o2 = o0, o3 = o0;
#pragma unroll
    for (int c = 0; c < CIN; ++c) {
        float wv = W[c * COUT + co];
        o0 = fmaf(wv, sAgg[c * TT + tt0    ], o0);
        o1 = fmaf(wv, sAgg[c * TT + tt0 + 1], o1);
        o2 = fmaf(wv, sAgg[c * TT + tt0 + 2], o2);
        o3 = fmaf(wv, sAgg[c * TT + tt0 + 3], o3);
    }
    o0 = fmaxf(o0, 0.0f); o1 = fmaxf(o1, 0.0f);
    o2 = fmaxf(o2, 0.0f); o3 = fmaxf(o3, 0.0f);

    __syncthreads();
    float4 ov; ov.x = o0; ov.y = o1; ov.z = o2; ov.w = o3;
    *((float4*)&sAgg[co * TT + tt0]) = ov;
    __syncthreads();
    f32x4 r = *((const f32x4*)&sAgg[4 * t]);
    __builtin_nontemporal_store(r, (f32x4*)(out + (size_t)n * FEAT + 4 * t));
}

// ---------- launch ----------
extern "C" void kernel_launch(void* const* d_in, const int* in_sizes, int n_in,
                              void* d_out, int out_size, void* d_ws, size_t ws_size,
                              hipStream_t stream) {
    const float* x   = (const float*)d_in[0];
    const int*   ei  = (const int*)d_in[1];
    const float* ea  = (const float*)d_in[2];
    const float* W   = (const float*)d_in[3];
    const float* b   = (const float*)d_in[4];
    float* out = (float*)d_out;

    const int E = in_sizes[2];
    const int N = in_sizes[0] / FEAT;
    const int* src = ei;
    const int* dst = ei + E;

    size_t off = 0;
    char* ws = (char*)d_ws;
    auto alloc = [&](size_t bytes) -> char* {
        char* p = ws + off;
        off = (off + bytes + 15) & ~(size_t)15;
        return p;
    };
    u64*   deg64   = (u64*)  alloc((size_t)N * 8);
    float* dis     = (float*)alloc((size_t)N * 4);
    int*   rowptr  = (int*)  alloc((size_t)(N + 1) * 4);
    int*   cursor  = (int*)  alloc((size_t)N * 4);
    int*   partial = (int*)  alloc(4096);
    int2*  csr     = (int2*) alloc((size_t)E * 8);
    uint32* xh2    = (uint32*)alloc((size_t)N * FEAT * 2);
    const bool use_bf16 = (off <= ws_size);

    int nb_n   = (N + 255) / 256;    // 196 for N=50000; must be <= 256
    int nb_e   = (E + 255) / 256;
    int nunits = N * 32;             // (node, channel-pair) transpose-cvt units
    int halfU  = nunits / 2;
    int nbCvt  = use_bf16 ? 1024 : 0;

    (void)hipMemsetAsync(deg64, 0, (size_t)N * 8, stream);
    // L1: deg atomics + cvt units [0, halfU)
    k_deg_cvt  <<<nbCvt + nb_e, 256, 0, stream>>>(x, xh2, 0, halfU, nbCvt,
                                                  dst, ea, deg64, E);
    k_disred   <<<nb_n, 256, 0, stream>>>(deg64, dis, partial, N);
    k_scanwrite<<<nb_n, 256, 0, stream>>>(deg64, partial, nb_n, rowptr, cursor, N);
    // L4: CSR fill + cvt units [halfU, nunits)
    k_fill_cvt <<<nbCvt + nb_e, 256, 0, stream>>>(x, xh2, halfU, nunits, nbCvt,
                                                  src, dst, ea, dis, cursor, csr, E);
    if (use_bf16) {
        k_conv2<<<N, 192, 0, stream>>>(xh2, W, b, dis, rowptr, csr, out, 0);
        k_conv2<<<N, 192, 0, stream>>>(xh2, W, b, dis, rowptr, csr, out, 1);
    } else {
        k_conv_f32<<<N, 192, 0, stream>>>(x, W, b, dis, rowptr, csr, out);
    }
}

// Round 10
// 313.550 us; speedup vs baseline: 1.4206x; 1.4206x over previous
//
#include <hip/hip_runtime.h>

#define CIN   64
#define COUT  64
#define TT    12
#define FEAT  (CIN * TT)   // 768
#define XROW  96           // uint4 (8 bf16) per row

typedef unsigned int uint32;
typedef unsigned long long u64;
typedef float  __attribute__((ext_vector_type(4))) f32x4;

#define DEG_SCALE 1048576.0f   // 2^20 fixed point for edge-weight sums

__device__ __forceinline__ void cvt_range(const f32x4* __restrict__ x,
                                          uint2* __restrict__ xh,
                                          int qlo, int qhi, int tid, int stride) {
    for (int i = qlo + tid; i < qhi; i += stride) {
        f32x4 v = __builtin_nontemporal_load(&x[i]);   // read-once stream
        uint32 u0 = __float_as_uint(v.x), u1 = __float_as_uint(v.y);
        uint32 u2 = __float_as_uint(v.z), u3 = __float_as_uint(v.w);
        u0 = (u0 + 0x7fffu + ((u0 >> 16) & 1)) >> 16;
        u1 = (u1 + 0x7fffu + ((u1 >> 16) & 1)) >> 16;
        u2 = (u2 + 0x7fffu + ((u2 >> 16) & 1)) >> 16;
        u3 = (u3 + 0x7fffu + ((u3 >> 16) & 1)) >> 16;
        uint2 o; o.x = u0 | (u1 << 16); o.y = u2 | (u3 << 16);
        xh[i] = o;
    }
}

// ---------- L1: degree atomics + cvt half A ----------
__global__ __launch_bounds__(256) void k_deg_cvt(
    const f32x4* __restrict__ x, uint2* __restrict__ xh, int qlo, int qhi, int nbCvt,
    const int* __restrict__ dst, const float* __restrict__ ea,
    u64* __restrict__ deg64, int e_cnt)
{
    int bid = blockIdx.x;
    if (bid < nbCvt) {
        cvt_range(x, xh, qlo, qhi, bid * 256 + threadIdx.x, nbCvt * 256);
    } else {
        int e = (bid - nbCvt) * 256 + threadIdx.x;
        if (e < e_cnt) {
            u64 v = ((u64)1 << 32) | (u64)(uint32)(ea[e] * DEG_SCALE + 0.5f);
            atomicAdd(&deg64[dst[e]], v);
        }
    }
}

// ---------- L2: dis = rsqrt(1 + sum_ea); block-reduce cnt into partial[] ----------
__global__ __launch_bounds__(256) void k_disred(const u64* __restrict__ deg64,
                                                float* __restrict__ dis,
                                                int* __restrict__ partial, int n) {
    __shared__ int red[256];
    int t = threadIdx.x;
    int i = blockIdx.x * 256 + t;
    int cnt = 0;
    if (i < n) {
        u64 v = deg64[i];
        cnt = (int)(v >> 32);
        dis[i] = rsqrtf(1.0f + (float)(uint32)v * (1.0f / DEG_SCALE));
    }
    red[t] = cnt;
    __syncthreads();
    for (int off = 128; off > 0; off >>= 1) {
        if (t < off) red[t] += red[t + off];
        __syncthreads();
    }
    if (t == 0) partial[blockIdx.x] = red[0];
}

// ---------- L3: per-element scan; each block redundantly reduces partial[] ----------
__global__ __launch_bounds__(256) void k_scanwrite(const u64* __restrict__ deg64,
                                                   const int* __restrict__ partial,
                                                   int nb,
                                                   int* __restrict__ rowptr,
                                                   int* __restrict__ cursor, int n) {
    __shared__ int tmp[256];
    __shared__ int pred[256];
    int t = threadIdx.x;
    int bid = blockIdx.x;
    int i = bid * 256 + t;

    int pv = (t < nb) ? partial[t] : 0;
    pred[t] = (t < bid) ? pv : 0;
    int v = (i < n) ? (int)(deg64[i] >> 32) : 0;
    tmp[t] = v;
    __syncthreads();
    for (int off = 128; off > 0; off >>= 1) {
        if (t < off) pred[t] += pred[t + off];
        __syncthreads();
    }
    for (int off = 1; off < 256; off <<= 1) {
        int u = (t >= off) ? tmp[t - off] : 0;
        __syncthreads();
        tmp[t] += u;
        __syncthreads();
    }
    int blockOff = pred[0];
    int excl = tmp[t] - v + blockOff;
    if (i < n) { rowptr[i] = excl; cursor[i] = excl; }
    if (bid == nb - 1 && t == 255) rowptr[n] = blockOff + tmp[255];
}

// ---------- L4: scatter edges into CSR slots + cvt half B ----------
__global__ __launch_bounds__(256) void k_fill_cvt(
    const f32x4* __restrict__ x, uint2* __restrict__ xh, int qlo, int qhi, int nbCvt,
    const int* __restrict__ src, const int* __restrict__ dst,
    const float* __restrict__ ea, const float* __restrict__ dis,
    int* __restrict__ cursor, int2* __restrict__ csr, int e_cnt)
{
    int bid = blockIdx.x;
    if (bid < nbCvt) {
        cvt_range(x, xh, qlo, qhi, bid * 256 + threadIdx.x, nbCvt * 256);
    } else {
        int e = (bid - nbCvt) * 256 + threadIdx.x;
        if (e < e_cnt) {
            int s = src[e], d = dst[e];
            int pos = atomicAdd(&cursor[d], 1);
            float w = dis[s] * ea[e] * dis[d];
            int2 p; p.x = s; p.y = __float_as_int(w);
            csr[pos] = p;
        }
    }
}

// ---------- fused aggregate + GEMM + bias + ReLU ----------
// one block per node, 192 threads = 2 edge-groups of 96 lanes.
// Per pair of edges: group eh handles edge 2j+eh with ONE dwordx4 (16B = 8 bf16)
// per lane -> 1.5 wave-load instructions per edge (vs 3 with dwordx2).
__global__ __launch_bounds__(192) void k_conv(
    const uint4* __restrict__ xb4, const float* __restrict__ W,
    const float* __restrict__ b, const float* __restrict__ dis,
    const int* __restrict__ rowptr, const int2* __restrict__ csr,
    float* __restrict__ out)
{
    __shared__ float sAgg[FEAT];   // 3 KB
    __shared__ int2  sE[192];      // 1.5 KB
    __shared__ float sB[COUT];

    const int n = blockIdx.x;
    const int t = threadIdx.x;
    if (t < COUT) sB[t] = b[t];

    const int eh = t / 96;         // edge-group 0/1
    const int tl = t - eh * 96;    // lane within group: owns bf16 feats [8tl, 8tl+8)

    const int start = rowptr[n];
    const int end   = rowptr[n + 1];
    const float dn  = dis[n];
    const float selfw = dn * dn;

    float a0 = 0, a1 = 0, a2 = 0, a3 = 0, a4 = 0, a5 = 0, a6 = 0, a7 = 0;
    if (eh == 0) {   // self-loop into group 0's partials
        uint4 v = xb4[(size_t)n * XROW + tl];
        a0 = selfw * __uint_as_float(v.x << 16);
        a1 = selfw * __uint_as_float(v.x & 0xffff0000u);
        a2 = selfw * __uint_as_float(v.y << 16);
        a3 = selfw * __uint_as_float(v.y & 0xffff0000u);
        a4 = selfw * __uint_as_float(v.z << 16);
        a5 = selfw * __uint_as_float(v.z & 0xffff0000u);
        a6 = selfw * __uint_as_float(v.w << 16);
        a7 = selfw * __uint_as_float(v.w & 0xffff0000u);
    }

    for (int base = start; base < end; base += 192) {
        int cnt = end - base; if (cnt > 192) cnt = 192;
        __syncthreads();
        if (t < cnt) sE[t] = csr[base + t];
        __syncthreads();
        int npair = (cnt + 1) >> 1;
        for (int j = 0; j < npair; ++j) {
            int j2 = 2 * j + eh;
            if (j2 < cnt) {
                int s    = sE[j2].x;
                float w  = __int_as_float(sE[j2].y);
                uint4 v = xb4[(size_t)s * XROW + tl];
                a0 = fmaf(w, __uint_as_float(v.x << 16),         a0);
                a1 = fmaf(w, __uint_as_float(v.x & 0xffff0000u), a1);
                a2 = fmaf(w, __uint_as_float(v.y << 16),         a2);
                a3 = fmaf(w, __uint_as_float(v.y & 0xffff0000u), a3);
                a4 = fmaf(w, __uint_as_float(v.z << 16),         a4);
                a5 = fmaf(w, __uint_as_float(v.z & 0xffff0000u), a5);
                a6 = fmaf(w, __uint_as_float(v.w << 16),         a6);
                a7 = fmaf(w, __uint_as_float(v.w & 0xffff0000u), a7);
            }
        }
    }

    // combine the two edge-groups' partials in sAgg
    if (eh == 0) {
        float4 lo; lo.x = a0; lo.y = a1; lo.z = a2; lo.w = a3;
        float4 hi; hi.x = a4; hi.y = a5; hi.z = a6; hi.w = a7;
        *((float4*)&sAgg[8 * tl])     = lo;
        *((float4*)&sAgg[8 * tl + 4]) = hi;
    }
    __syncthreads();
    if (eh == 1) {
        sAgg[8 * tl    ] += a0; sAgg[8 * tl + 1] += a1;
        sAgg[8 * tl + 2] += a2; sAgg[8 * tl + 3] += a3;
        sAgg[8 * tl + 4] += a4; sAgg[8 * tl + 5] += a5;
        sAgg[8 * tl + 6] += a6; sAgg[8 * tl + 7] += a7;
    }
    __syncthreads();

    // GEMM epilogue (R8 proven): out[co,tt] = relu(b[co] + sum_c W[c,co]*agg[c,tt])
    const int co  = t & 63;
    const int tg  = t >> 6;              // wave-uniform
    const int tt0 = tg * 4;
    float o0 = sB[co], o1 = o0, o2 = o0, o3 = o0;
#pragma unroll
    for (int c = 0; c < CIN; ++c) {
        float wv = W[c * COUT + co];     // hot 16 KB in L1/L2
        o0 = fmaf(wv, sAgg[c * TT + tt0    ], o0);
        o1 = fmaf(wv, sAgg[c * TT + tt0 + 1], o1);
        o2 = fmaf(wv, sAgg[c * TT + tt0 + 2], o2);
        o3 = fmaf(wv, sAgg[c * TT + tt0 + 3], o3);
    }
    o0 = fmaxf(o0, 0.0f); o1 = fmaxf(o1, 0.0f);
    o2 = fmaxf(o2, 0.0f); o3 = fmaxf(o3, 0.0f);

    __syncthreads();
    float4 ov; ov.x = o0; ov.y = o1; ov.z = o2; ov.w = o3;
    *((float4*)&sAgg[co * TT + tt0]) = ov;
    __syncthreads();
    f32x4 r = *((const f32x4*)&sAgg[4 * t]);
    __builtin_nontemporal_store(r, (f32x4*)(out + (size_t)n * FEAT + 4 * t));
}

// ---------- fallback (ws too small): fp32 gather (R5 structure) ----------
__global__ __launch_bounds__(192) void k_conv_f32(
    const float* __restrict__ xsrc, const float* __restrict__ W,
    const float* __restrict__ b, const float* __restrict__ dis,
    const int* __restrict__ rowptr, const int2* __restrict__ csr,
    float* __restrict__ out)
{
    __shared__ float sAgg[FEAT];
    __shared__ int2  sE[192];
    __shared__ float sB[COUT];

    const int n = blockIdx.x;
    const int t = threadIdx.x;
    if (t < COUT) sB[t] = b[t];

    const int start = rowptr[n];
    const int end   = rowptr[n + 1];
    const float dn  = dis[n];
    const float selfw = dn * dn;

    const f32x4* xb = (const f32x4*)xsrc;
    f32x4 v = xb[(size_t)n * (FEAT / 4) + t];
    float a0 = selfw * v.x, a1 = selfw * v.y, a2 = selfw * v.z, a3 = selfw * v.w;

    for (int base = start; base < end; base += 192) {
        int cnt = end - base; if (cnt > 192) cnt = 192;
        __syncthreads();
        if (t < cnt) sE[t] = csr[base + t];
        __syncthreads();
        for (int j = 0; j < cnt; ++j) {
            int s    = sE[j].x;
            float w  = __int_as_float(sE[j].y);
            f32x4 u = xb[(size_t)s * (FEAT / 4) + t];
            a0 = fmaf(w, u.x, a0); a1 = fmaf(w, u.y, a1);
            a2 = fmaf(w, u.z, a2); a3 = fmaf(w, u.w, a3);
        }
    }

    float4 av; av.x = a0; av.y = a1; av.z = a2; av.w = a3;
    *((float4*)&sAgg[4 * t]) = av;
    __syncthreads();

    const int co  = t & 63;
    const int tg  = t >> 6;
    const int tt0 = tg * 4;
    float o0 = sB[co], o1 = o0, o2 = o0, o3 = o0;
#pragma unroll
    for (int c = 0; c < CIN; ++c) {
        float wv = W[c * COUT + co];
        o0 = fmaf(wv, sAgg[c * TT + tt0    ], o0);
        o1 = fmaf(wv, sAgg[c * TT + tt0 + 1], o1);
        o2 = fmaf(wv, sAgg[c * TT + tt0 + 2], o2);
        o3 = fmaf(wv, sAgg[c * TT + tt0 + 3], o3);
    }
    o0 = fmaxf(o0, 0.0f); o1 = fmaxf(o1, 0.0f);
    o2 = fmaxf(o2, 0.0f); o3 = fmaxf(o3, 0.0f);

    __syncthreads();
    float4 ov; ov.x = o0; ov.y = o1; ov.z = o2; ov.w = o3;
    *((float4*)&sAgg[co * TT + tt0]) = ov;
    __syncthreads();
    f32x4 r = *((const f32x4*)&sAgg[4 * t]);
    __builtin_nontemporal_store(r, (f32x4*)(out + (size_t)n * FEAT + 4 * t));
}

// ---------- launch ----------
extern "C" void kernel_launch(void* const* d_in, const int* in_sizes, int n_in,
                              void* d_out, int out_size, void* d_ws, size_t ws_size,
                              hipStream_t stream) {
    const float* x   = (const float*)d_in[0];
    const int*   ei  = (const int*)d_in[1];
    const float* ea  = (const float*)d_in[2];
    const float* W   = (const float*)d_in[3];
    const float* b   = (const float*)d_in[4];
    float* out = (float*)d_out;

    const int E = in_sizes[2];
    const int N = in_sizes[0] / FEAT;
    const int* src = ei;
    const int* dst = ei + E;

    size_t off = 0;
    char* ws = (char*)d_ws;
    auto alloc = [&](size_t bytes) -> char* {
        char* p = ws + off;
        off = (off + bytes + 15) & ~(size_t)15;
        return p;
    };
    u64*   deg64   = (u64*)  alloc((size_t)N * 8);
    float* dis     = (float*)alloc((size_t)N * 4);
    int*   rowptr  = (int*)  alloc((size_t)(N + 1) * 4);
    int*   cursor  = (int*)  alloc((size_t)N * 4);
    int*   partial = (int*)  alloc(4096);
    int2*  csr     = (int2*) alloc((size_t)E * 8);
    unsigned short* xh = (unsigned short*)alloc((size_t)N * FEAT * 2);
    const bool use_bf16 = (off <= ws_size);

    int nb_n   = (N + 255) / 256;    // 196 for N=50000; must be <= 256
    int nb_e   = (E + 255) / 256;
    int nquads = (N * FEAT) / 4;
    int halfQ  = nquads / 2;
    int nbCvt  = use_bf16 ? 1024 : 0;

    (void)hipMemsetAsync(deg64, 0, (size_t)N * 8, stream);
    // L1: deg atomics + cvt quads [0, halfQ)
    k_deg_cvt  <<<nbCvt + nb_e, 256, 0, stream>>>((const f32x4*)x, (uint2*)xh,
                                                  0, halfQ, nbCvt, dst, ea, deg64, E);
    k_disred   <<<nb_n, 256, 0, stream>>>(deg64, dis, partial, N);
    k_scanwrite<<<nb_n, 256, 0, stream>>>(deg64, partial, nb_n, rowptr, cursor, N);
    // L4: CSR fill + cvt quads [halfQ, nquads)
    k_fill_cvt <<<nbCvt + nb_e, 256, 0, stream>>>((const f32x4*)x, (uint2*)xh,
                                                  halfQ, nquads, nbCvt,
                                                  src, dst, ea, dis, cursor, csr, E);
    if (use_bf16)
        k_conv<<<N, 192, 0, stream>>>((const uint4*)xh, W, b, dis, rowptr, csr, out);
    else
        k_conv_f32<<<N, 192, 0, stream>>>(x, W, b, dis, rowptr, csr, out);
}

// Round 11
// 310.982 us; speedup vs baseline: 1.4323x; 1.0083x over previous
//
#include <hip/hip_runtime.h>

#define CIN   64
#define COUT  64
#define TT    12
#define FEAT  (CIN * TT)   // 768
#define QROW  (FEAT / 4)   // 192 uint2 (4 bf16) per row

typedef unsigned int uint32;
typedef unsigned long long u64;
typedef float  __attribute__((ext_vector_type(4))) f32x4;

#define DEG_SCALE 1048576.0f   // 2^20 fixed point for edge-weight sums

__device__ __forceinline__ void cvt_range(const f32x4* __restrict__ x,
                                          uint2* __restrict__ xh,
                                          int qlo, int qhi, int tid, int stride) {
    for (int i = qlo + tid; i < qhi; i += stride) {
        f32x4 v = __builtin_nontemporal_load(&x[i]);   // read-once stream
        uint32 u0 = __float_as_uint(v.x), u1 = __float_as_uint(v.y);
        uint32 u2 = __float_as_uint(v.z), u3 = __float_as_uint(v.w);
        u0 = (u0 + 0x7fffu + ((u0 >> 16) & 1)) >> 16;
        u1 = (u1 + 0x7fffu + ((u1 >> 16) & 1)) >> 16;
        u2 = (u2 + 0x7fffu + ((u2 >> 16) & 1)) >> 16;
        u3 = (u3 + 0x7fffu + ((u3 >> 16) & 1)) >> 16;
        uint2 o; o.x = u0 | (u1 << 16); o.y = u2 | (u3 << 16);
        xh[i] = o;
    }
}

// ---------- L1: degree atomics + cvt half A ----------
__global__ __launch_bounds__(256) void k_deg_cvt(
    const f32x4* __restrict__ x, uint2* __restrict__ xh, int qlo, int qhi, int nbCvt,
    const int* __restrict__ dst, const float* __restrict__ ea,
    u64* __restrict__ deg64, int e_cnt)
{
    int bid = blockIdx.x;
    if (bid < nbCvt) {
        cvt_range(x, xh, qlo, qhi, bid * 256 + threadIdx.x, nbCvt * 256);
    } else {
        int e = (bid - nbCvt) * 256 + threadIdx.x;
        if (e < e_cnt) {
            u64 v = ((u64)1 << 32) | (u64)(uint32)(ea[e] * DEG_SCALE + 0.5f);
            atomicAdd(&deg64[dst[e]], v);
        }
    }
}

// ---------- L2: dis = rsqrt(1 + sum_ea); block-reduce cnt into partial[] ----------
__global__ __launch_bounds__(256) void k_disred(const u64* __restrict__ deg64,
                                                float* __restrict__ dis,
                                                int* __restrict__ partial, int n) {
    __shared__ int red[256];
    int t = threadIdx.x;
    int i = blockIdx.x * 256 + t;
    int cnt = 0;
    if (i < n) {
        u64 v = deg64[i];
        cnt = (int)(v >> 32);
        dis[i] = rsqrtf(1.0f + (float)(uint32)v * (1.0f / DEG_SCALE));
    }
    red[t] = cnt;
    __syncthreads();
    for (int off = 128; off > 0; off >>= 1) {
        if (t < off) red[t] += red[t + off];
        __syncthreads();
    }
    if (t == 0) partial[blockIdx.x] = red[0];
}

// ---------- L3: per-element scan; each block redundantly reduces partial[] ----------
// nb (number of partials) must be <= 256
__global__ __launch_bounds__(256) void k_scanwrite(const u64* __restrict__ deg64,
                                                   const int* __restrict__ partial,
                                                   int nb,
                                                   int* __restrict__ rowptr,
                                                   int* __restrict__ cursor, int n) {
    __shared__ int tmp[256];
    __shared__ int pred[256];
    int t = threadIdx.x;
    int bid = blockIdx.x;
    int i = bid * 256 + t;

    int pv = (t < nb) ? partial[t] : 0;
    pred[t] = (t < bid) ? pv : 0;
    int v = (i < n) ? (int)(deg64[i] >> 32) : 0;
    tmp[t] = v;
    __syncthreads();
    for (int off = 128; off > 0; off >>= 1) {
        if (t < off) pred[t] += pred[t + off];
        __syncthreads();
    }
    for (int off = 1; off < 256; off <<= 1) {
        int u = (t >= off) ? tmp[t - off] : 0;
        __syncthreads();
        tmp[t] += u;
        __syncthreads();
    }
    int blockOff = pred[0];
    int excl = tmp[t] - v + blockOff;
    if (i < n) { rowptr[i] = excl; cursor[i] = excl; }
    if (bid == nb - 1 && t == 255) rowptr[n] = blockOff + tmp[255];
}

// ---------- L4: scatter edges into CSR slots + cvt half B ----------
__global__ __launch_bounds__(256) void k_fill_cvt(
    const f32x4* __restrict__ x, uint2* __restrict__ xh, int qlo, int qhi, int nbCvt,
    const int* __restrict__ src, const int* __restrict__ dst,
    const float* __restrict__ ea, const float* __restrict__ dis,
    int* __restrict__ cursor, int2* __restrict__ csr, int e_cnt)
{
    int bid = blockIdx.x;
    if (bid < nbCvt) {
        cvt_range(x, xh, qlo, qhi, bid * 256 + threadIdx.x, nbCvt * 256);
    } else {
        int e = (bid - nbCvt) * 256 + threadIdx.x;
        if (e < e_cnt) {
            int s = src[e], d = dst[e];
            int pos = atomicAdd(&cursor[d], 1);
            float w = dis[s] * ea[e] * dis[d];
            int2 p; p.x = s; p.y = __float_as_int(w);
            csr[pos] = p;
        }
    }
}

// ---------- fused aggregate + GEMM + bias + ReLU (R8 proven best) ----------
// one block per node, 192 threads; thread t owns features [4t, 4t+4)
template <int BF16>
__global__ __launch_bounds__(192) void k_conv(
    const void* __restrict__ xsrc, const float* __restrict__ W,
    const float* __restrict__ b, const float* __restrict__ dis,
    const int* __restrict__ rowptr, const int2* __restrict__ csr,
    float* __restrict__ out)
{
    __shared__ float sAgg[FEAT];   // 3 KB
    __shared__ int2  sE[192];      // 1.5 KB
    __shared__ float sB[COUT];

    const int n = blockIdx.x;
    const int t = threadIdx.x;
    if (t < COUT) sB[t] = b[t];

    const int start = rowptr[n];
    const int end   = rowptr[n + 1];
    const float dn  = dis[n];
    const float selfw = dn * dn;

    float a0, a1, a2, a3;
    if (BF16) {
        const uint2* xb = (const uint2*)xsrc;
        uint2 v = xb[(size_t)n * QROW + t];
        a0 = selfw * __uint_as_float(v.x << 16);
        a1 = selfw * __uint_as_float(v.x & 0xffff0000u);
        a2 = selfw * __uint_as_float(v.y << 16);
        a3 = selfw * __uint_as_float(v.y & 0xffff0000u);
    } else {
        const f32x4* xb = (const f32x4*)xsrc;
        f32x4 v = xb[(size_t)n * QROW + t];
        a0 = selfw * v.x; a1 = selfw * v.y; a2 = selfw * v.z; a3 = selfw * v.w;
    }

    for (int base = start; base < end; base += 192) {
        int cnt = end - base; if (cnt > 192) cnt = 192;
        __syncthreads();
        if (t < cnt) sE[t] = csr[base + t];
        __syncthreads();
        for (int j = 0; j < cnt; ++j) {
            int s    = sE[j].x;
            float w  = __int_as_float(sE[j].y);
            if (BF16) {
                const uint2* xb = (const uint2*)xsrc;
                uint2 v = xb[(size_t)s * QROW + t];
                a0 = fmaf(w, __uint_as_float(v.x << 16),         a0);
                a1 = fmaf(w, __uint_as_float(v.x & 0xffff0000u), a1);
                a2 = fmaf(w, __uint_as_float(v.y << 16),         a2);
                a3 = fmaf(w, __uint_as_float(v.y & 0xffff0000u), a3);
            } else {
                const f32x4* xb = (const f32x4*)xsrc;
                f32x4 v = xb[(size_t)s * QROW + t];
                a0 = fmaf(w, v.x, a0); a1 = fmaf(w, v.y, a1);
                a2 = fmaf(w, v.z, a2); a3 = fmaf(w, v.w, a3);
            }
        }
    }

    float4 av; av.x = a0; av.y = a1; av.z = a2; av.w = a3;
    *((float4*)&sAgg[4 * t]) = av;
    __syncthreads();

    const int co  = t & 63;
    const int tg  = t >> 6;              // wave-uniform
    const int tt0 = tg * 4;
    float o0 = sB[co], o1 = o0, o2 = o0, o3 = o0;
#pragma unroll
    for (int c = 0; c < CIN; ++c) {
        float wv = W[c * COUT + co];     // hot 16 KB in L1/L2
        o0 = fmaf(wv, sAgg[c * TT + tt0    ], o0);
        o1 = fmaf(wv, sAgg[c * TT + tt0 + 1], o1);
        o2 = fmaf(wv, sAgg[c * TT + tt0 + 2], o2);
        o3 = fmaf(wv, sAgg[c * TT + tt0 + 3], o3);
    }
    o0 = fmaxf(o0, 0.0f); o1 = fmaxf(o1, 0.0f);
    o2 = fmaxf(o2, 0.0f); o3 = fmaxf(o3, 0.0f);

    __syncthreads();
    float4 ov; ov.x = o0; ov.y = o1; ov.z = o2; ov.w = o3;
    *((float4*)&sAgg[co * TT + tt0]) = ov;
    __syncthreads();
    f32x4 r = *((const f32x4*)&sAgg[4 * t]);
    __builtin_nontemporal_store(r, (f32x4*)(out + (size_t)n * FEAT + 4 * t));
}

// ---------- launch ----------
extern "C" void kernel_launch(void* const* d_in, const int* in_sizes, int n_in,
                              void* d_out, int out_size, void* d_ws, size_t ws_size,
                              hipStream_t stream) {
    const float* x   = (const float*)d_in[0];
    const int*   ei  = (const int*)d_in[1];
    const float* ea  = (const float*)d_in[2];
    const float* W   = (const float*)d_in[3];
    const float* b   = (const float*)d_in[4];
    float* out = (float*)d_out;

    const int E = in_sizes[2];
    const int N = in_sizes[0] / FEAT;
    const int* src = ei;
    const int* dst = ei + E;

    size_t off = 0;
    char* ws = (char*)d_ws;
    auto alloc = [&](size_t bytes) -> char* {
        char* p = ws + off;
        off = (off + bytes + 15) & ~(size_t)15;
        return p;
    };
    u64*   deg64   = (u64*)  alloc((size_t)N * 8);
    float* dis     = (float*)alloc((size_t)N * 4);
    int*   rowptr  = (int*)  alloc((size_t)(N + 1) * 4);
    int*   cursor  = (int*)  alloc((size_t)N * 4);
    int*   partial = (int*)  alloc(4096);
    int2*  csr     = (int2*) alloc((size_t)E * 8);
    unsigned short* xh = (unsigned short*)alloc((size_t)N * FEAT * 2);
    const bool use_bf16 = (off <= ws_size);

    int nb_n   = (N + 255) / 256;    // 196 for N=50000; must be <= 256
    int nb_e   = (E + 255) / 256;
    int nquads = (N * FEAT) / 4;
    int halfQ  = nquads / 2;
    int nbCvt  = use_bf16 ? 1024 : 0;

    (void)hipMemsetAsync(deg64, 0, (size_t)N * 8, stream);
    // L1: deg atomics + cvt quads [0, halfQ)
    k_deg_cvt  <<<nbCvt + nb_e, 256, 0, stream>>>((const f32x4*)x, (uint2*)xh,
                                                  0, halfQ, nbCvt, dst, ea, deg64, E);
    k_disred   <<<nb_n, 256, 0, stream>>>(deg64, dis, partial, N);
    k_scanwrite<<<nb_n, 256, 0, stream>>>(deg64, partial, nb_n, rowptr, cursor, N);
    // L4: CSR fill + cvt quads [halfQ, nquads)
    k_fill_cvt <<<nbCvt + nb_e, 256, 0, stream>>>((const f32x4*)x, (uint2*)xh,
                                                  halfQ, nquads, nbCvt,
                                                  src, dst, ea, dis, cursor, csr, E);
    if (use_bf16)
        k_conv<1><<<N, 192, 0, stream>>>(xh, W, b, dis, rowptr, csr, out);
    else
        k_conv<0><<<N, 192, 0, stream>>>(x,  W, b, dis, rowptr, csr, out);
}